// Round 1
// baseline (335.735 us; speedup 1.0000x reference)
//
#include <hip/hip_runtime.h>

#define B  8
#define N  8192
#define M  2048
#define C  64
#define CT 64
#define K  32
#define R2 0.04f   // nearest f32 to 0.2*0.2, matches jnp/np promotion

__device__ __forceinline__ float rfl(float x) {
    union { float f; int i; } u;
    u.f = x;
    u.i = __builtin_amdgcn_readfirstlane(u.i);
    return u.f;
}

// ---------------------------------------------------------------------------
// Kernel 1: transpose feats/temb [B,64,N] -> [B,N,64]; points [B,3,N] ->
// [B,N,4] with .w = px^2+py^2+pz^2 (exact np op order).
// Inner logic verbatim from the verified kernel (absmax 0.0); changes:
//   - batch<->XCD affinity: b = blockIdx % 8 (XCDs round-robin on blockIdx),
//     so batch b's pointsT is written by (and stays dirty in) XCD b's L2.
//   - NT loads of single-use src, NT stores of featsT/tembT (33 MB stream
//     that exceeds L2 anyway); pointsT stores stay cached (0.5 MB/batch,
//     re-read by ballquery on the SAME XCD).
// ---------------------------------------------------------------------------
__global__ __launch_bounds__(256) void transpose_kernel(
    const float* __restrict__ points,   // [B,3,N]
    const float* __restrict__ temb,     // [B,CT,N]
    const float* __restrict__ feats,    // [B,C,N]
    float* __restrict__ pointsT,        // [B,N,4]
    float* __restrict__ tembT,          // [B,N,64]
    float* __restrict__ featsT)         // [B,N,64]
{
    const int gx = blockIdx.x;
    if (gx < 2048) {
        const int b  = gx & 7;            // XCD affinity: batch = blockIdx % 8
        const int r  = gx >> 3;           // 0..255
        const int a  = r >> 7;            // 0: feats, 1: temb
        const int n0 = (r & 127) << 6;
        const float* src = (a ? temb : feats) + (size_t)b * 64 * N;
        float* dst = (a ? tembT : featsT) + (size_t)b * N * 64;
        __shared__ float lds[64][65];
        const int nl = threadIdx.x & 63;
        const int c0 = threadIdx.x >> 6;   // 0..3
        #pragma unroll
        for (int i = 0; i < 16; ++i) {
            const int c = c0 + i * 4;
            lds[c][nl] = __builtin_nontemporal_load(&src[(size_t)c * N + n0 + nl]);
        }
        __syncthreads();
        #pragma unroll
        for (int i = 0; i < 16; ++i) {
            const int n = c0 + i * 4;
            __builtin_nontemporal_store(lds[nl][n],
                                        &dst[(size_t)(n0 + n) * 64 + nl]);
        }
    } else {
        const int tt = gx - 2048;          // 2048 % 8 == 0, so XCD = tt % 8
        const int b  = tt & 7;
        const int n  = ((tt >> 3) << 8) + threadIdx.x;
        const float* pc = points + (size_t)b * 3 * N;
        float* dst = pointsT + ((size_t)b * N + n) * 4;
        const float px = pc[n];
        const float py = pc[N + n];
        const float pz = pc[2 * N + n];
        dst[0] = px;
        dst[1] = py;
        dst[2] = pz;
        dst[3] = __fadd_rn(__fadd_rn(__fmul_rn(px, px), __fmul_rn(py, py)),
                           __fmul_rn(pz, pz));   // pn^2, np op order
    }
}

// one 64-point chunk. d2 replicates np op order exactly:
// (cn + pn) - 2*cross, no fma contraction. pn^2 precomputed in vv.w.
// Verbatim (correctness-verified).
#define PROC(vv, nn)                                                          \
    do {                                                                      \
        const float cross = __fadd_rn(                                        \
            __fadd_rn(__fmul_rn(cx, (vv).x), __fmul_rn(cy, (vv).y)),          \
            __fmul_rn(cz, (vv).z));                                           \
        const float d2 = __fsub_rn(__fadd_rn(cn, (vv).w),                     \
                                   __fmul_rn(2.0f, cross));                   \
        const bool valid = d2 < R2;                                           \
        const unsigned long long mask = __ballot(valid);                      \
        if (valid) {                                                          \
            const int slot = cnt + __builtin_amdgcn_mbcnt_hi(                 \
                (unsigned)(mask >> 32),                                       \
                __builtin_amdgcn_mbcnt_lo((unsigned)mask, 0));                \
            if (slot < K) snp[slot] = (nn);                                   \
        }                                                                     \
        cnt += (int)__popcll(mask);                                           \
    } while (0)

// ---------------------------------------------------------------------------
// Kernel 2: ball query only (was phase 0 of the fused kernel, verbatim scan).
// One wave per center, 4 centers/block. Tiny LDS (512 B) -> high occupancy,
// so the heavy-tailed scan (boundary centers scan 2-8x more points) is
// averaged over ~16+ resident blocks/CU instead of stalling gather barriers.
// Working set = pointsT[b] = 0.5 MB: fully L2-resident on its own XCD.
// Writes final (fill-fixed) idx to workspace; same-XCD gather reads it back.
// ---------------------------------------------------------------------------
__global__ __launch_bounds__(256) void ballquery_kernel(
    const float* __restrict__ pointsT,  // [B,N,4] (.w = pn^2)
    const float* __restrict__ centers,  // [B,3,M]
    int* __restrict__ idx)              // [B,M,K]
{
    __shared__ int sn[128];
    const int bid = blockIdx.x;
    const int b   = bid & 7;            // XCD affinity
    const int m0  = (bid >> 3) << 2;
    const int t    = threadIdx.x;
    const int wv   = t >> 6;
    const int lane = t & 63;
    const int m    = m0 + wv;

    const float cx = rfl(centers[((size_t)b * 3 + 0) * M + m]);
    const float cy = rfl(centers[((size_t)b * 3 + 1) * M + m]);
    const float cz = rfl(centers[((size_t)b * 3 + 2) * M + m]);
    const float cn = rfl(__fadd_rn(
        __fadd_rn(__fmul_rn(cx, cx), __fmul_rn(cy, cy)),
        __fmul_rn(cz, cz)));

    int* snp = &sn[wv * K];
    if (lane == 0) snp[0] = 0;          // default fill for empty ball

    const float4* pt4 = (const float4*)(pointsT + (size_t)b * N * 4);
    int cnt = 0;
    float4 va[4], vb[4];
    #pragma unroll
    for (int j = 0; j < 4; ++j) va[j] = pt4[j * 64 + lane];

    for (int g = 0; g < 32; g += 2) {
        if (g + 1 < 32) {
            #pragma unroll
            for (int j = 0; j < 4; ++j)
                vb[j] = pt4[((g + 1) * 4 + j) * 64 + lane];
        }
        #pragma unroll
        for (int j = 0; j < 4; ++j) PROC(va[j], g * 256 + j * 64 + lane);
        if (cnt >= K || g + 1 >= 32) break;

        if (g + 2 < 32) {
            #pragma unroll
            for (int j = 0; j < 4; ++j)
                va[j] = pt4[((g + 2) * 4 + j) * 64 + lane];
        }
        #pragma unroll
        for (int j = 0; j < 4; ++j) PROC(vb[j], (g + 1) * 256 + j * 64 + lane);
        if (cnt >= K) break;
    }

    // fill slots >= cnt with first valid index (same-wave LDS, no barrier
    // needed — identical ordering to the verified fused kernel)
    if (lane < K) {
        const int fill = snp[0];
        const int v    = snp[lane];
        idx[((size_t)b * M + m) * K + lane] = (lane < cnt) ? v : fill;
    }
}

// ---------------------------------------------------------------------------
// Kernel 3: gather/store (was phases 1-3, verbatim) with:
//   - sn loaded from workspace idx (coalesced, same-XCD L2 hit)
//   - NT stores for the 274 MB output stream so it stops write-allocating
//     through (and evicting) the 4.2 MB featsT/tembT gather tables in L2.
// ---------------------------------------------------------------------------
__global__ __launch_bounds__(256) void gather_kernel(
    const float* __restrict__ pointsT,  // [B,N,4]
    const float* __restrict__ centers,  // [B,3,M]
    const float* __restrict__ tembT,    // [B,N,64]
    const float* __restrict__ featsT,   // [B,N,64]
    const int*   __restrict__ idx,      // [B,M,K]
    float* __restrict__ out1,           // [B,3+C,M,K]
    float* __restrict__ out2)           // [B,CT,M,K]
{
    __shared__ int   sn[128];
    __shared__ float tile[128 * 65];
    __shared__ float ctile[3][128];

    const int t   = threadIdx.x;
    const int bid = blockIdx.x;
    const int b   = bid & 7;            // XCD affinity (matches ballquery)
    const int m0  = (bid >> 3) << 2;
    const size_t base_mk = (size_t)m0 * K;
    const size_t cs = (size_t)M * K;

    if (t < 128) sn[t] = idx[((size_t)b * M + m0) * K + t];
    __syncthreads();

    const int cq = t & 15;     // float4 slot: channels cq*4 .. cq*4+3
    const int pl = t >> 4;     // 0..15
    const float* fT = featsT + (size_t)b * N * 64;
    const float* tT = tembT  + (size_t)b * N * 64;

    // ---- phase 1: feats -> out1 channels 3..66 ----
    #pragma unroll
    for (int i = 0; i < 8; ++i) {
        const int p = i * 16 + pl;
        const int n = sn[p];
        const float4 v = *(const float4*)(fT + (size_t)n * 64 + cq * 4);
        float* d = &tile[p * 65 + cq * 4];
        d[0] = v.x; d[1] = v.y; d[2] = v.z; d[3] = v.w;
    }
    __syncthreads();
    {
        const int p   = t & 127;
        const int ch0 = t >> 7;    // 0..1
        float* o = out1 + (size_t)b * 67 * cs + 3 * cs + base_mk + p;
        #pragma unroll
        for (int i = 0; i < 32; ++i) {
            const int c = ch0 + i * 2;
            __builtin_nontemporal_store(tile[p * 65 + c], &o[(size_t)c * cs]);
        }
    }
    __syncthreads();

    // ---- phase 2: temb -> out2 channels 0..63 ----
    #pragma unroll
    for (int i = 0; i < 8; ++i) {
        const int p = i * 16 + pl;
        const int n = sn[p];
        const float4 v = *(const float4*)(tT + (size_t)n * 64 + cq * 4);
        float* d = &tile[p * 65 + cq * 4];
        d[0] = v.x; d[1] = v.y; d[2] = v.z; d[3] = v.w;
    }
    __syncthreads();
    {
        const int p   = t & 127;
        const int ch0 = t >> 7;
        float* o = out2 + (size_t)b * 64 * cs + base_mk + p;
        #pragma unroll
        for (int i = 0; i < 32; ++i) {
            const int c = ch0 + i * 2;
            __builtin_nontemporal_store(tile[p * 65 + c], &o[(size_t)c * cs]);
        }
    }

    // ---- phase 3: coords -> out1 channels 0..2 (re-centered) ----
    if (t < 128) {
        const int p = t;
        const int n = sn[p];
        const int m = m0 + (p >> 5);
        const float4 v = *(const float4*)(pointsT + ((size_t)b * N + n) * 4);
        ctile[0][p] = v.x - centers[((size_t)b * 3 + 0) * M + m];
        ctile[1][p] = v.y - centers[((size_t)b * 3 + 1) * M + m];
        ctile[2][p] = v.z - centers[((size_t)b * 3 + 2) * M + m];
    }
    __syncthreads();
    {
        const int c = t >> 7;      // 0..1
        const int p = t & 127;
        __builtin_nontemporal_store(ctile[c][p],
            &out1[((size_t)b * 67 + c) * cs + base_mk + p]);
    }
    if (t < 128) {
        __builtin_nontemporal_store(ctile[2][t],
            &out1[((size_t)b * 67 + 2) * cs + base_mk + t]);
    }
}

extern "C" void kernel_launch(void* const* d_in, const int* in_sizes, int n_in,
                              void* d_out, int out_size, void* d_ws, size_t ws_size,
                              hipStream_t stream) {
    const float* points  = (const float*)d_in[0];  // [8,3,8192]
    const float* centers = (const float*)d_in[1];  // [8,3,2048]
    const float* temb    = (const float*)d_in[2];  // [8,64,8192]
    const float* feats   = (const float*)d_in[3];  // [8,64,8192]

    // workspace layout (35 MB)
    float* pointsT = (float*)d_ws;                            // 1 MB
    float* featsT  = pointsT + (size_t)B * N * 4;             // 16 MB
    float* tembT   = featsT  + (size_t)B * N * 64;            // 16 MB
    int*   idxws   = (int*)(tembT + (size_t)B * N * 64);      // 2 MB

    float* out1 = (float*)d_out;                              // [8,67,2048,32]
    float* out2 = out1 + (size_t)B * (3 + C) * M * K;         // [8,64,2048,32]

    transpose_kernel<<<2304, 256, 0, stream>>>(points, temb, feats,
                                               pointsT, tembT, featsT);
    ballquery_kernel<<<(B * M) / 4, 256, 0, stream>>>(pointsT, centers, idxws);
    gather_kernel<<<(B * M) / 4, 256, 0, stream>>>(pointsT, centers, tembT,
                                                   featsT, idxws, out1, out2);
}

// Round 3
// 324.489 us; speedup vs baseline: 1.0347x; 1.0347x over previous
//
#include <hip/hip_runtime.h>

#define B  8
#define N  8192
#define M  2048
#define C  64
#define CT 64
#define K  32
#define R2 0.04f   // nearest f32 to 0.2*0.2, matches jnp/np promotion

// clang-native vector types: __builtin_nontemporal_* rejects HIP_vector_type
typedef __attribute__((ext_vector_type(4))) float f4;
typedef __attribute__((ext_vector_type(4))) int   i4;

__device__ __forceinline__ float rfl(float x) {
    union { float f; int i; } u;
    u.f = x;
    u.i = __builtin_amdgcn_readfirstlane(u.i);
    return u.f;
}

// ---------------------------------------------------------------------------
// Kernel 1: points [B,3,N] -> pointsT [B,N,4] with .w = px^2+py^2+pz^2
// (exact np op order). feats/temb transpose is GONE — the new gather reads
// them in natural layout. Arithmetic verbatim from the verified kernel.
// ---------------------------------------------------------------------------
__global__ __launch_bounds__(256) void prep_points(
    const float* __restrict__ points,   // [B,3,N]
    float* __restrict__ pointsT)        // [B,N,4]
{
    const int b = blockIdx.x & 7;                 // XCD affinity
    const int n = ((blockIdx.x >> 3) << 8) + threadIdx.x;
    const float* pc = points + (size_t)b * 3 * N;
    float* dst = pointsT + ((size_t)b * N + n) * 4;
    const float px = pc[n];
    const float py = pc[N + n];
    const float pz = pc[2 * N + n];
    dst[0] = px;
    dst[1] = py;
    dst[2] = pz;
    dst[3] = __fadd_rn(__fadd_rn(__fmul_rn(px, px), __fmul_rn(py, py)),
                       __fmul_rn(pz, pz));   // pn^2, np op order
}

// one 64-point chunk. d2 replicates np op order exactly:
// (cn + pn) - 2*cross, no fma contraction. pn^2 precomputed in vv.w.
// Verbatim (correctness-verified).
#define PROC(vv, nn)                                                          \
    do {                                                                      \
        const float cross = __fadd_rn(                                        \
            __fadd_rn(__fmul_rn(cx, (vv).x), __fmul_rn(cy, (vv).y)),          \
            __fmul_rn(cz, (vv).z));                                           \
        const float d2 = __fsub_rn(__fadd_rn(cn, (vv).w),                     \
                                   __fmul_rn(2.0f, cross));                   \
        const bool valid = d2 < R2;                                           \
        const unsigned long long mask = __ballot(valid);                      \
        if (valid) {                                                          \
            const int slot = cnt + __builtin_amdgcn_mbcnt_hi(                 \
                (unsigned)(mask >> 32),                                       \
                __builtin_amdgcn_mbcnt_lo((unsigned)mask, 0));                \
            if (slot < K) snp[slot] = (nn);                                   \
        }                                                                     \
        cnt += (int)__popcll(mask);                                           \
    } while (0)

// ---------------------------------------------------------------------------
// Kernel 2: ball query (scan verbatim) + fused coord channels.
// One wave per center, 4 centers/block, tiny LDS -> high occupancy.
// New tail: lanes 0..31 write the fill-fixed idx AND out1 channels 0..2
// (pointsT[nf].xyz - center, same IEEE sub as the old phase-3; cx/cy/cz are
// rfl() of the same global loads -> bit-identical operands).
// ---------------------------------------------------------------------------
__global__ __launch_bounds__(256) void ballquery_kernel(
    const float* __restrict__ pointsT,  // [B,N,4] (.w = pn^2)
    const float* __restrict__ centers,  // [B,3,M]
    int* __restrict__ idx,              // [B,M,K]
    float* __restrict__ out1)           // [B,67,M,K] (writes ch 0..2)
{
    __shared__ int sn[128];
    const int bid = blockIdx.x;
    const int b   = bid & 7;            // XCD affinity
    const int m0  = (bid >> 3) << 2;
    const int t    = threadIdx.x;
    const int wv   = t >> 6;
    const int lane = t & 63;
    const int m    = m0 + wv;

    const float cx = rfl(centers[((size_t)b * 3 + 0) * M + m]);
    const float cy = rfl(centers[((size_t)b * 3 + 1) * M + m]);
    const float cz = rfl(centers[((size_t)b * 3 + 2) * M + m]);
    const float cn = rfl(__fadd_rn(
        __fadd_rn(__fmul_rn(cx, cx), __fmul_rn(cy, cy)),
        __fmul_rn(cz, cz)));

    int* snp = &sn[wv * K];
    if (lane == 0) snp[0] = 0;          // default fill for empty ball

    const float4* pt4 = (const float4*)(pointsT + (size_t)b * N * 4);
    int cnt = 0;
    float4 va[4], vb[4];
    #pragma unroll
    for (int j = 0; j < 4; ++j) va[j] = pt4[j * 64 + lane];

    for (int g = 0; g < 32; g += 2) {
        if (g + 1 < 32) {
            #pragma unroll
            for (int j = 0; j < 4; ++j)
                vb[j] = pt4[((g + 1) * 4 + j) * 64 + lane];
        }
        #pragma unroll
        for (int j = 0; j < 4; ++j) PROC(va[j], g * 256 + j * 64 + lane);
        if (cnt >= K || g + 1 >= 32) break;

        if (g + 2 < 32) {
            #pragma unroll
            for (int j = 0; j < 4; ++j)
                va[j] = pt4[((g + 2) * 4 + j) * 64 + lane];
        }
        #pragma unroll
        for (int j = 0; j < 4; ++j) PROC(vb[j], (g + 1) * 256 + j * 64 + lane);
        if (cnt >= K) break;
    }

    // fill slots >= cnt with first valid index (same-wave LDS ordering,
    // identical to the verified kernel), then emit idx + coord channels.
    if (lane < K) {
        const int fill = snp[0];
        const int v    = snp[lane];
        const int nf   = (lane < cnt) ? v : fill;
        idx[((size_t)b * M + m) * K + lane] = nf;

        const float4 p = *(const float4*)(pointsT + ((size_t)b * N + nf) * 4);
        const size_t cs = (size_t)M * K;
        const size_t o  = (size_t)b * 67 * cs + (size_t)m * K + lane;
        __builtin_nontemporal_store(p.x - cx, &out1[o]);
        __builtin_nontemporal_store(p.y - cy, &out1[o + cs]);
        __builtin_nontemporal_store(p.z - cz, &out1[o + 2 * cs]);
    }
}

// ---------------------------------------------------------------------------
// Kernel 3: channel-slab gather. Block = (batch, table, channel-pair).
// Stage the 2 contiguous channel rows (64 KB) in LDS, then sweep all M*K
// positions: random 4 B reads from LDS (cheap, ~4-way conflicts), perfectly
// contiguous float4 NT store streams per channel (fill-kernel-shaped HBM
// traffic). 512 blocks x 512 threads, 64 KB LDS -> 2 blocks/CU.
// Pure data movement, no arithmetic -> bit-exact by construction.
// ---------------------------------------------------------------------------
__global__ __launch_bounds__(512) void gather_kernel(
    const float* __restrict__ temb,     // [B,64,N] natural layout
    const float* __restrict__ feats,    // [B,64,N] natural layout
    const int*   __restrict__ idx,      // [B,M,K]
    float* __restrict__ out1,           // [B,67,M,K] (writes ch 3..66)
    float* __restrict__ out2)           // [B,64,M,K]
{
    __shared__ float row[2 * N];        // 64 KB: two channel rows

    const int bid  = blockIdx.x;
    const int b    = bid & 7;           // XCD affinity (idx[b] hot in XCD-b L2)
    const int slab = bid >> 3;          // 0..63
    const int tab  = slab >> 5;         // 0: feats, 1: temb
    const int c0   = (slab & 31) * 2;   // channel pair
    const int t    = threadIdx.x;

    // stage: channels c0,c0+1 are contiguous in [64][N] layout -> linear copy
    const f4* src4 = (const f4*)((tab ? temb : feats)
                                 + ((size_t)b * 64 + c0) * N);
    f4* lds4 = (f4*)row;
    #pragma unroll
    for (int i = 0; i < 8; ++i)
        lds4[i * 512 + t] = __builtin_nontemporal_load(&src4[i * 512 + t]);
    __syncthreads();

    const size_t cs = (size_t)M * K;
    float* o0 = tab ? (out2 + ((size_t)b * 64 + c0) * cs)
                    : (out1 + ((size_t)b * 67 + 3 + c0) * cs);
    f4* o0v = (f4*)o0;
    f4* o1v = (f4*)(o0 + cs);
    const i4* idx4 = (const i4*)(idx + (size_t)b * M * K);

    // 65536 positions, 4 per thread per iter, 512 threads -> 32 iters.
    // One-deep idx prefetch to hide the (L2-resident) index load.
    i4 nn = idx4[t];
    for (int it = 0; it < 32; ++it) {
        const int q = it * 512 + t;     // int4 / float4 position index
        const i4 cur = nn;
        if (it < 31) nn = idx4[q + 512];
        f4 v0, v1;
        v0.x = row[cur.x];     v0.y = row[cur.y];
        v0.z = row[cur.z];     v0.w = row[cur.w];
        v1.x = row[N + cur.x]; v1.y = row[N + cur.y];
        v1.z = row[N + cur.z]; v1.w = row[N + cur.w];
        __builtin_nontemporal_store(v0, &o0v[q]);
        __builtin_nontemporal_store(v1, &o1v[q]);
    }
}

extern "C" void kernel_launch(void* const* d_in, const int* in_sizes, int n_in,
                              void* d_out, int out_size, void* d_ws, size_t ws_size,
                              hipStream_t stream) {
    const float* points  = (const float*)d_in[0];  // [8,3,8192]
    const float* centers = (const float*)d_in[1];  // [8,3,2048]
    const float* temb    = (const float*)d_in[2];  // [8,64,8192]
    const float* feats   = (const float*)d_in[3];  // [8,64,8192]

    // workspace layout (3 MB)
    float* pointsT = (float*)d_ws;                        // [8,8192,4]  1 MB
    int*   idxws   = (int*)(pointsT + (size_t)B * N * 4); // [8,2048,32] 2 MB

    float* out1 = (float*)d_out;                          // [8,67,2048,32]
    float* out2 = out1 + (size_t)B * (3 + C) * M * K;     // [8,64,2048,32]

    prep_points<<<(B * N) / 256, 256, 0, stream>>>(points, pointsT);
    ballquery_kernel<<<(B * M) / 4, 256, 0, stream>>>(pointsT, centers,
                                                      idxws, out1);
    gather_kernel<<<B * 2 * 32, 512, 0, stream>>>(temb, feats, idxws,
                                                  out1, out2);
}